// Round 1
// baseline (4204.350 us; speedup 1.0000x reference)
//
#include <hip/hip_runtime.h>
#include <cstdint>
#include <cstddef>

typedef _Float16 half8 __attribute__((ext_vector_type(8)));
typedef float floatx4 __attribute__((ext_vector_type(4)));

#define FLAG_RES  1
#define FLAG_GELU 2
#define FLAG_W32  4
#define FLAG_W16  8
#define FLAG_PART 16

// Fast exact-GELU: erf via Abramowitz-Stegun 7.1.26 (|err| <= 1.5e-7), __expf.
__device__ __forceinline__ float gelu_exact(float x) {
    const float z = fabsf(x) * 0.70710678118654752f;
    const float t = 1.f / fmaf(0.3275911f, z, 1.f);
    const float p = t * (0.254829592f + t * (-0.284496736f +
                     t * (1.421413741f + t * (-1.453152027f + t * 1.061405429f))));
    const float erfa = 1.f - p * __expf(-z * z);
    return 0.5f * x * (1.f + copysignf(erfa, x));
}

// async global->LDS (16B/lane): dest is wave-uniform base + lane*16.
typedef const __attribute__((address_space(1))) void GV;
typedef __attribute__((address_space(3))) void LV;
__device__ __forceinline__ void gl_lds16(const void* g, void* l) {
    __builtin_amdgcn_global_load_lds((GV*)g, (LV*)l, 16, 0, 0);
}

// ---------------------------------------------------------------------------
// GEMM: C(MxN) = A(MxK f16 rm) @ Bt(NxK f16 rm)^T + bias(fp32)
// 128x256 tile, BK=32, 256 thr (2x2 waves, each 64x128). Staging via
// global_load_lds dwordx4 with XOR source-pre-swizzle (chunk ^= (row>>1)&3)
// so the ds_read_b128 fragment reads are ~conflict-free. LDS ping-pong,
// ONE barrier per K-step (next-tile loads issued right after the barrier,
// drained by the compiler's vmcnt(0) at the NEXT barrier -> full overlap).
// blockIdx.z = split-K slice of length klen (klen%32==0). FLAG_PART writes
// raw fp32 partials to out32 + z*M*N. Epilogue guards gn<N (N=128 case).
// ---------------------------------------------------------------------------
__global__ __launch_bounds__(256, 2) void gemm_f16(
    const _Float16* __restrict__ A, const _Float16* __restrict__ Bt,
    const float* __restrict__ bias, const float* __restrict__ resid,
    float* __restrict__ out32, _Float16* __restrict__ out16,
    int M, int N, int K, int klen, int flags)
{
    __shared__ __align__(16) _Float16 As[2][128 * 32];
    __shared__ __align__(16) _Float16 Bs[2][256 * 32];
    const int tid = threadIdx.x;
    const int wid = tid >> 6;
    const int lane = tid & 63;
    const int bm = blockIdx.y * 128;
    const int bn = blockIdx.x * 256;
    const int wr = wid >> 1, wc = wid & 1;
    const int lane15 = lane & 15, quad = lane >> 4;
    const int kb = blockIdx.z * klen;

    floatx4 acc[4][8];
#pragma unroll
    for (int i = 0; i < 4; i++)
#pragma unroll
        for (int j = 0; j < 8; j++)
            acc[i][j] = floatx4{0.f, 0.f, 0.f, 0.f};

    // staging map: lane -> row rr (16-row group), 16B chunk ch; source chunk
    // pre-swizzled so LDS (linear dest) ends up XOR-swizzled.
    const int rr = lane >> 2;
    const int ch = lane & 3;
    const _Float16* asrc[2];
    const _Float16* bsrc[4];
#pragma unroll
    for (int g = 0; g < 2; g++) {
        const int r = wid * 32 + g * 16 + rr;
        const int cs = ch ^ ((r >> 1) & 3);
        asrc[g] = A + (size_t)(bm + r) * K + kb + cs * 8;
    }
#pragma unroll
    for (int g = 0; g < 4; g++) {
        const int r = wid * 64 + g * 16 + rr;
        const int cs = ch ^ ((r >> 1) & 3);
        int br = bn + r; if (br > N - 1) br = N - 1;   // guard (values discarded)
        bsrc[g] = Bt + (size_t)br * K + kb + cs * 8;
    }

    // fragment LDS offsets (halfs), swizzle-matched, constant across K loop
    int aoff[4], boff[8];
#pragma unroll
    for (int mi = 0; mi < 4; mi++) {
        const int r = wr * 64 + mi * 16 + lane15;
        aoff[mi] = r * 32 + ((quad ^ ((r >> 1) & 3)) << 3);
    }
#pragma unroll
    for (int ni = 0; ni < 8; ni++) {
        const int r = wc * 128 + ni * 16 + lane15;
        boff[ni] = r * 32 + ((quad ^ ((r >> 1) & 3)) << 3);
    }

    const int nk = klen >> 5;
    {   // prologue: tile 0 -> buffer 0
        _Float16* ab = &As[0][wid * 1024];
        _Float16* bb = &Bs[0][wid * 2048];
#pragma unroll
        for (int g = 0; g < 2; g++) gl_lds16(asrc[g], ab + g * 512);
#pragma unroll
        for (int g = 0; g < 4; g++) gl_lds16(bsrc[g], bb + g * 512);
    }
    for (int ik = 0; ik < nk; ik++) {
        __syncthreads();   // compiler drains vmcnt -> tile ik resident; prior reads closed
        if (ik + 1 < nk) {
            const int ko = (ik + 1) << 5;
            _Float16* ab = &As[(ik + 1) & 1][wid * 1024];
            _Float16* bb = &Bs[(ik + 1) & 1][wid * 2048];
#pragma unroll
            for (int g = 0; g < 2; g++) gl_lds16(asrc[g] + ko, ab + g * 512);
#pragma unroll
            for (int g = 0; g < 4; g++) gl_lds16(bsrc[g] + ko, bb + g * 512);
        }
        const _Float16* a_ = As[ik & 1];
        const _Float16* b_ = Bs[ik & 1];
        half8 af[4], bf[8];
#pragma unroll
        for (int mi = 0; mi < 4; mi++) af[mi] = *(const half8*)&a_[aoff[mi]];
#pragma unroll
        for (int ni = 0; ni < 8; ni++) bf[ni] = *(const half8*)&b_[boff[ni]];
#pragma unroll
        for (int mi = 0; mi < 4; mi++)
#pragma unroll
            for (int ni = 0; ni < 8; ni++)
                acc[mi][ni] = __builtin_amdgcn_mfma_f32_16x16x32_f16(
                    af[mi], bf[ni], acc[mi][ni], 0, 0, 0);
    }

    // epilogue: C/D layout col = lane&15, row = quad*4 + reg
    if (flags & FLAG_PART) {
        float* po = out32 + (size_t)blockIdx.z * ((size_t)M * N);
#pragma unroll
        for (int mi = 0; mi < 4; mi++) {
            const int gmb = bm + wr * 64 + mi * 16 + quad * 4;
#pragma unroll
            for (int ni = 0; ni < 8; ni++) {
                const int gn = bn + wc * 128 + ni * 16 + lane15;
                if (gn < N) {
#pragma unroll
                    for (int r = 0; r < 4; r++)
                        po[(size_t)(gmb + r) * N + gn] = acc[mi][ni][r];
                }
            }
        }
        return;
    }
#pragma unroll
    for (int mi = 0; mi < 4; mi++) {
        const int gmb = bm + wr * 64 + mi * 16 + quad * 4;
#pragma unroll
        for (int ni = 0; ni < 8; ni++) {
            const int gn = bn + wc * 128 + ni * 16 + lane15;
            if (gn >= N) continue;
            const float bv = bias[gn];
#pragma unroll
            for (int r = 0; r < 4; r++) {
                float v = acc[mi][ni][r] + bv;
                if (flags & FLAG_GELU) v = gelu_exact(v);
                const size_t off = (size_t)(gmb + r) * N + gn;
                if (flags & FLAG_RES) v += resid[off];
                if (flags & FLAG_W32) out32[off] = v;
                if (flags & FLAG_W16) out16[off] = (_Float16)v;
            }
        }
    }
}

// ---------------------------------------------------------------------------
// Split-K reduce: out[i] = gelu(bias[i%N] + sum_z part[z*MN + i]) as f16.
// ---------------------------------------------------------------------------
__global__ __launch_bounds__(256) void skred_k(
    const float* __restrict__ part, const float* __restrict__ bias,
    _Float16* __restrict__ out, int MN, int N, int S)
{
    const int i = blockIdx.x * 256 + threadIdx.x;
    if (i >= MN) return;
    float s = bias[i % N];
    for (int z = 0; z < S; z++) s += part[(size_t)z * MN + i];
    out[i] = (_Float16)gelu_exact(s);
}

// ---------------------------------------------------------------------------
// Fused split-K reduce (S=4, N=128) + gelu + final (128x3) matmul + bias.
// One wave per batch row; lanes hold 2 cols each; butterfly-reduce 3 dots.
// ---------------------------------------------------------------------------
__global__ __launch_bounds__(256) void skcls_k(
    const float* __restrict__ part, const float* __restrict__ b2,
    const float* __restrict__ w3, const float* __restrict__ b3,
    float* __restrict__ out, int CH)
{
    const int wid = threadIdx.x >> 6, lane = threadIdx.x & 63;
    const int b = blockIdx.x * 4 + wid;
    const size_t MN = (size_t)CH * 128;
    const int c0 = lane, c1 = lane + 64;
    float s0 = b2[c0], s1 = b2[c1];
#pragma unroll
    for (int z = 0; z < 4; z++) {
        s0 += part[z * MN + (size_t)b * 128 + c0];
        s1 += part[z * MN + (size_t)b * 128 + c1];
    }
    const float g0 = gelu_exact(s0), g1 = gelu_exact(s1);
    float a0 = g0 * w3[c0 * 3 + 0] + g1 * w3[c1 * 3 + 0];
    float a1 = g0 * w3[c0 * 3 + 1] + g1 * w3[c1 * 3 + 1];
    float a2 = g0 * w3[c0 * 3 + 2] + g1 * w3[c1 * 3 + 2];
#pragma unroll
    for (int m = 32; m >= 1; m >>= 1) {
        a0 += __shfl_xor(a0, m, 64);
        a1 += __shfl_xor(a1, m, 64);
        a2 += __shfl_xor(a2, m, 64);
    }
    if (lane == 0) {
        out[b * 3 + 0] = a0 + b3[0];
        out[b * 3 + 1] = a1 + b3[1];
        out[b * 3 + 2] = a2 + b3[2];
    }
}

// ---------------------------------------------------------------------------
// Row LayerNorm over 512 cols: fp32 in, fp32 params, f16 out. One wave/row.
// ---------------------------------------------------------------------------
__global__ __launch_bounds__(256) void ln_rows(
    const float* __restrict__ x, const float* __restrict__ w,
    const float* __restrict__ b, _Float16* __restrict__ out)
{
    const int wid = threadIdx.x >> 6, lane = threadIdx.x & 63;
    const size_t row = (size_t)blockIdx.x * 4 + wid;
    const int c0 = lane * 8;
    const float* xr = x + row * 512 + c0;
    float4 v0 = *(const float4*)xr;
    float4 v1 = *(const float4*)(xr + 4);
    float xv[8] = {v0.x, v0.y, v0.z, v0.w, v1.x, v1.y, v1.z, v1.w};
    float s = 0.f, q = 0.f;
#pragma unroll
    for (int j = 0; j < 8; j++) { s += xv[j]; q += xv[j] * xv[j]; }
#pragma unroll
    for (int m = 32; m >= 1; m >>= 1) {
        s += __shfl_xor(s, m, 64);
        q += __shfl_xor(q, m, 64);
    }
    const float mean = s * (1.f / 512.f);
    const float rstd = rsqrtf(q * (1.f / 512.f) - mean * mean + 1e-5f);
    half8 o;
#pragma unroll
    for (int j = 0; j < 8; j++)
        o[j] = (_Float16)((xv[j] - mean) * rstd * w[c0 + j] + b[c0 + j]);
    *(half8*)&out[row * 512 + c0] = o;
}

// ---------------------------------------------------------------------------
// Attention: 4 (b,head) units per 256-thread block (one wave each).
// ---------------------------------------------------------------------------
__global__ __launch_bounds__(256) void attn_k(
    const _Float16* __restrict__ qkv, _Float16* __restrict__ o)
{
    __shared__ float qs[4][12][65], ks[4][12][65], vs[4][12][65];
    __shared__ float att[4][12][16];
    const int wid = threadIdx.x >> 6, lane = threadIdx.x & 63;
    const int unit = blockIdx.x * 4 + wid;
    const int b = unit >> 3, hd = unit & 7;
    const _Float16* base = qkv + (size_t)b * (12 * 1536) + hd * 64 + lane;
#pragma unroll
    for (int r = 0; r < 12; r++) {
        qs[wid][r][lane] = (float)base[r * 1536];
        ks[wid][r][lane] = (float)base[r * 1536 + 512];
        vs[wid][r][lane] = (float)base[r * 1536 + 1024];
    }
    __syncthreads();
#pragma unroll
    for (int i = 0; i < 3; i++) {
        const int p = lane + i * 64;
        if (p < 144) {
            const int qi = p / 12, kj = p - qi * 12;
            float d = 0.f;
            for (int e = 0; e < 64; e++) d += qs[wid][qi][e] * ks[wid][kj][e];
            att[wid][qi][kj] = d * 0.125f;
        }
    }
    __syncthreads();
    if (lane < 12) {
        float mx = att[wid][lane][0];
#pragma unroll
        for (int j = 1; j < 12; j++) mx = fmaxf(mx, att[wid][lane][j]);
        float ev[12], ssum = 0.f;
#pragma unroll
        for (int j = 0; j < 12; j++) { ev[j] = expf(att[wid][lane][j] - mx); ssum += ev[j]; }
        const float inv = 1.f / ssum;
#pragma unroll
        for (int j = 0; j < 12; j++) att[wid][lane][j] = ev[j] * inv;
    }
    __syncthreads();
    _Float16* ob = o + (size_t)b * (12 * 512) + hd * 64 + lane;
#pragma unroll
    for (int qi = 0; qi < 12; qi++) {
        float s = 0.f;
#pragma unroll
        for (int j = 0; j < 12; j++) s += att[wid][qi][j] * vs[wid][j][lane];
        ob[qi * 512] = (_Float16)s;
    }
}

// ---------------------------------------------------------------------------
// Fused factors + per-(batch,feature) time-norm -> (CH*12, 96) f16 patch rows.
// Two-pass recompute: pass1 accumulates stats, pass2 writes normalized f16.
// cl/vl in LDS are per-thread spill columns (no cross-thread sharing).
// ---------------------------------------------------------------------------
struct FSt { float e12, e26, ag, al, s1c, s2c, s1v; };

__device__ __forceinline__ void fderiv(
    int t, float c, float cprev, float co, float v, float vprev, float vo,
    FSt& s, float f[6])
{
    const float a12 = 2.f / 13.f, a26 = 2.f / 27.f, a14 = 1.f / 14.f;
    const float sv = v > 0.f ? v : 1.f;
    if (t > 0) {
        s.e12 = a12 * c + (1.f - a12) * s.e12;
        s.e26 = a26 * c + (1.f - a26) * s.e26;
    }
    const float macd = s.e12 - s.e26;
    const float delta = t > 0 ? c - cprev : 0.f;
    if (t > 0) {
        s.ag = a14 * fmaxf(delta, 0.f) + (1.f - a14) * s.ag;
        s.al = a14 * fmaxf(-delta, 0.f) + (1.f - a14) * s.al;
    }
    const float rs = s.ag / (s.al + 1e-10f);
    const float rsi = (100.f - 100.f / (1.f + rs)) * 0.01f;
    s.s1c += c; s.s2c += c * c; s.s1v += sv;
    if (t >= 20) {
        const float svo = vo > 0.f ? vo : 1.f;
        s.s1c -= co; s.s2c -= co * co; s.s1v -= svo;
    }
    float bb = 0.f, vmr = 1.f;
    if (t >= 19) {
        const float mean = s.s1c * 0.05f;
        const float sq = s.s2c * 0.05f;
        const float sd = sqrtf(fmaxf(sq - mean * mean, 0.f));
        bb = 4.f * sd / (mean + 1e-8f);
        vmr = sv / (s.s1v * 0.05f + 1e-8f);
    }
    float lr = 0.f, lv = 0.f;
    if (t > 0) {
        lr = logf(fmaxf(c, 1e-8f) / fmaxf(cprev, 1e-8f));
        const float svp = vprev > 0.f ? vprev : 1.f;
        lv = logf(sv / (svp + 1e-8f));
    }
    f[0] = isfinite(macd) ? macd : 0.f;
    f[1] = isfinite(rsi) ? rsi : 0.f;
    f[2] = isfinite(bb) ? bb : 0.f;
    f[3] = isfinite(lr) ? lr : 0.f;
    f[4] = isfinite(lv) ? lv : 0.f;
    f[5] = isfinite(vmr) ? vmr : 0.f;
}

__global__ __launch_bounds__(64) void factors_k(
    const float* __restrict__ x, const float* __restrict__ in_w,
    const float* __restrict__ in_b, _Float16* __restrict__ feats, int CH)
{
    const int tid = threadIdx.x;
    const int b = blockIdx.x * 64 + tid;
    if (b >= CH) return;
    __shared__ float cl[96][64];
    __shared__ float vl[96][64];
    const float* xb = x + (size_t)b * 480;

    float sum[11], ssq[11];
#pragma unroll
    for (int f = 0; f < 11; f++) { sum[f] = 0.f; ssq[f] = 0.f; }

    // stage close/vol + accumulate raw-col (f=0..4) stats in one pass
    for (int t = 0; t < 96; t++) {
        const float* xq = xb + t * 5;
        const float a0 = xq[0], a1 = xq[1], a2 = xq[2], c = xq[3], v = xq[4];
        cl[t][tid] = c; vl[t][tid] = v;
        sum[0] += a0; ssq[0] += a0 * a0;
        sum[1] += a1; ssq[1] += a1 * a1;
        sum[2] += a2; ssq[2] += a2 * a2;
        sum[3] += c;  ssq[3] += c * c;
        sum[4] += v;  ssq[4] += v * v;
    }

    // pass 1: derived-feature stats
    {
        const float c0 = cl[0][tid];
        FSt st{c0, c0, 0.f, 0.f, 0.f, 0.f, 0.f};
        for (int t = 0; t < 96; t++) {
            const float c = cl[t][tid], v = vl[t][tid];
            const float cp = t > 0 ? cl[t - 1][tid] : 0.f;
            const float vp = t > 0 ? vl[t - 1][tid] : 0.f;
            const float co = t >= 20 ? cl[t - 20][tid] : 0.f;
            const float vo = t >= 20 ? vl[t - 20][tid] : 0.f;
            float f6[6];
            fderiv(t, c, cp, co, v, vp, vo, st, f6);
#pragma unroll
            for (int j = 0; j < 6; j++) { sum[5 + j] += f6[j]; ssq[5 + j] += f6[j] * f6[j]; }
        }
    }
    float scale[11], shift[11];
#pragma unroll
    for (int f = 0; f < 11; f++) {
        const float m = sum[f] * (1.f / 96.f);
        const float var = ssq[f] * (1.f / 96.f) - m * m;
        const float r = rsqrtf(var + 1e-5f);
        scale[f] = r * in_w[f];
        shift[f] = in_b[f] - m * scale[f];
    }

    // pass 2: recompute, write normalized f16 patch rows + zero pad cols 88..95
    {
        const float c0 = cl[0][tid];
        FSt st{c0, c0, 0.f, 0.f, 0.f, 0.f, 0.f};
        _Float16* orow = feats + (size_t)b * 1152;
        for (int t = 0; t < 96; t++) {
            const float c = cl[t][tid], v = vl[t][tid];
            const float cp = t > 0 ? cl[t - 1][tid] : 0.f;
            const float vp = t > 0 ? vl[t - 1][tid] : 0.f;
            const float co = t >= 20 ? cl[t - 20][tid] : 0.f;
            const float vo = t >= 20 ? vl[t - 20][tid] : 0.f;
            float f6[6];
            fderiv(t, c, cp, co, v, vp, vo, st, f6);
            const float* xq = xb + t * 5;
            float o[11] = {xq[0], xq[1], xq[2], c, v, f6[0], f6[1], f6[2], f6[3], f6[4], f6[5]};
            _Float16* op = orow + (t >> 3) * 96 + (t & 7) * 11;
#pragma unroll
            for (int f = 0; f < 11; f++)
                op[f] = (_Float16)(o[f] * scale[f] + shift[f]);
        }
        const int4 z4 = {0, 0, 0, 0};
#pragma unroll
        for (int p = 0; p < 12; p++)
            *(int4*)(orow + p * 96 + 88) = z4;
    }
}

// ---------------------------------------------------------------------------
// Tiled transpose + cast, z-batched: W (K x N) fp32 -> Wt (N x Kpad) f16.
// ---------------------------------------------------------------------------
__global__ __launch_bounds__(256) void tr_k(
    const float* __restrict__ W, _Float16* __restrict__ Wt,
    int K, int N, int Kpad, long long ss, long long ds)
{
    W  += (size_t)blockIdx.z * ss;
    Wt += (size_t)blockIdx.z * ds;
    __shared__ _Float16 t[32][33];
    const int n0 = blockIdx.x * 32, k0 = blockIdx.y * 32;
#pragma unroll
    for (int j = 0; j < 4; j++) {
        const int k = k0 + threadIdx.y + j * 8;
        t[threadIdx.y + j * 8][threadIdx.x] =
            (k < K) ? (_Float16)W[(size_t)k * N + n0 + threadIdx.x] : (_Float16)0.f;
    }
    __syncthreads();
#pragma unroll
    for (int j = 0; j < 4; j++) {
        const int n = n0 + threadIdx.y + j * 8;
        Wt[(size_t)n * Kpad + k0 + threadIdx.x] = t[threadIdx.x][threadIdx.y + j * 8];
    }
}

// ---------------------------------------------------------------------------
extern "C" void kernel_launch(void* const* d_in, const int* in_sizes, int n_in,
                              void* d_out, int out_size, void* d_ws, size_t ws_size,
                              hipStream_t stream)
{
    static const int EXP[23] = {1966080, 11, 11, 45056, 512, 2048, 2048,
        3145728, 6144, 1048576, 2048, 2048, 2048, 4194304, 8192, 4194304, 2048,
        3145728, 512, 65536, 128, 384, 3};
    static const int S2D[23] = {18, 20, 22, 17, 19, 21, 2, 1, 6, 5, 12, 11,
        14, 16, 13, 15, 10, 9, 4, 3, 8, 7, 0};
    const void* in[23];
    if (n_in != 23 || out_size != 12288) return;
    bool ok = true;
    for (int i = 0; i < 23; i++) ok = ok && (in_sizes[i] == EXP[i]);
    if (ok) {
        for (int i = 0; i < 23; i++) in[i] = d_in[i];
    } else {
        bool ok2 = true;
        for (int s = 0; s < 23; s++) ok2 = ok2 && (in_sizes[s] == EXP[S2D[s]]);
        if (!ok2) return;
        for (int s = 0; s < 23; s++) in[S2D[s]] = d_in[s];
    }
    const float* x      = (const float*)in[0];
    const float* in_w   = (const float*)in[1];
    const float* in_b   = (const float*)in[2];
    const float* pe_w   = (const float*)in[3];
    const float* pe_b   = (const float*)in[4];
    const float* ln1_w  = (const float*)in[5];
    const float* ln1_b  = (const float*)in[6];
    const float* qkv_w  = (const float*)in[7];
    const float* qkv_b  = (const float*)in[8];
    const float* out_w  = (const float*)in[9];
    const float* out_b  = (const float*)in[10];
    const float* ln2_w  = (const float*)in[11];
    const float* ln2_b  = (const float*)in[12];
    const float* mlp_w1 = (const float*)in[13];
    const float* mlp_b1 = (const float*)in[14];
    const float* mlp_w2 = (const float*)in[15];
    const float* mlp_b2 = (const float*)in[16];
    const float* cls_w1 = (const float*)in[17];
    const float* cls_b1 = (const float*)in[18];
    const float* cls_w2 = (const float*)in[19];
    const float* cls_b2 = (const float*)in[20];
    const float* cls_w3 = (const float*)in[21];
    const float* cls_b3 = (const float*)in[22];

    // ---- f16 weight arena (~31.7 MB) ----
    char* ws = (char*)d_ws;
    size_t off = 0;
    _Float16* wt_pe  = (_Float16*)(ws + off); off += (size_t)512 * 96 * 2;
    _Float16* wt_qkv = (_Float16*)(ws + off); off += (size_t)4 * 1536 * 512 * 2;
    _Float16* wt_out = (_Float16*)(ws + off); off += (size_t)4 * 512 * 512 * 2;
    _Float16* wt_m1  = (_Float16*)(ws + off); off += (size_t)4 * 2048 * 512 * 2;
    _Float16* wt_m2  = (_Float16*)(ws + off); off += (size_t)4 * 512 * 2048 * 2;
    _Float16* wt_c1  = (_Float16*)(ws + off); off += (size_t)512 * 6144 * 2;
    _Float16* wt_c2  = (_Float16*)(ws + off); off += (size_t)128 * 512 * 2;
    const size_t wbytes = off;

    // adaptive chunk: per-batch bytes = h32 24576 + abuf 12288 + bbuf 49152
    const size_t per = 86016 + 64;
    int CH = 4096;
    while (CH > 128 && wbytes + (size_t)CH * per > ws_size) CH >>= 1;
    const int nch = 4096 / CH;
    const int M = CH * 12;

    float*    h32  = (float*)(ws + off);    off += (size_t)M * 512 * 4;
    _Float16* abuf = (_Float16*)(ws + off); off += (size_t)M * 512 * 2;
    _Float16* bbuf = (_Float16*)(ws + off); off += (size_t)M * 2048 * 2;

    _Float16* feats = bbuf;                 // dead after pe GEMM
    _Float16* f1 = (_Float16*)h32;          // classifier temp (h32 dead then)
    float* part1 = (float*)bbuf;                          // 8*CH*512 fp32
    float* part2 = part1 + (size_t)8 * CH * 512;          // 4*CH*128 fp32

    // ---- weight prep: fp32 (K,N) -> f16 (N,Kpad) transposed, z-batched ----
    tr_k<<<dim3(16, 3, 1),   dim3(32, 8), 0, stream>>>(pe_w, wt_pe, 88, 512, 96, 0, 0);
    tr_k<<<dim3(48, 16, 4),  dim3(32, 8), 0, stream>>>(qkv_w, wt_qkv, 512, 1536, 512,
        (long long)512 * 1536, (long long)1536 * 512);
    tr_k<<<dim3(16, 16, 4),  dim3(32, 8), 0, stream>>>(out_w, wt_out, 512, 512, 512,
        (long long)512 * 512, (long long)512 * 512);
    tr_k<<<dim3(64, 16, 4),  dim3(32, 8), 0, stream>>>(mlp_w1, wt_m1, 512, 2048, 512,
        (long long)512 * 2048, (long long)2048 * 512);
    tr_k<<<dim3(16, 64, 4),  dim3(32, 8), 0, stream>>>(mlp_w2, wt_m2, 2048, 512, 2048,
        (long long)2048 * 512, (long long)512 * 2048);
    tr_k<<<dim3(16, 192, 1), dim3(32, 8), 0, stream>>>(cls_w1, wt_c1, 6144, 512, 6144, 0, 0);
    tr_k<<<dim3(4, 16, 1),   dim3(32, 8), 0, stream>>>(cls_w2, wt_c2, 512, 128, 512, 0, 0);

    for (int c = 0; c < nch; c++) {
        const float* xc = x + (size_t)c * CH * 480;
        factors_k<<<CH / 64, 64, 0, stream>>>(xc, in_w, in_b, feats, CH);
        gemm_f16<<<dim3(2, M / 128), 256, 0, stream>>>(
            feats, wt_pe, pe_b, nullptr, h32, nullptr, M, 512, 96, 96, FLAG_W32);

        for (int i = 0; i < 4; i++) {
            ln_rows<<<M / 4, 256, 0, stream>>>(h32, ln1_w + i * 512, ln1_b + i * 512, abuf);
            gemm_f16<<<dim3(6, M / 128), 256, 0, stream>>>(
                abuf, wt_qkv + (size_t)i * 1536 * 512, qkv_b + i * 1536,
                nullptr, nullptr, bbuf, M, 1536, 512, 512, FLAG_W16);
            attn_k<<<CH * 2, 256, 0, stream>>>(bbuf, abuf);
            gemm_f16<<<dim3(2, M / 128), 256, 0, stream>>>(
                abuf, wt_out + (size_t)i * 512 * 512, out_b + i * 512,
                h32, h32, nullptr, M, 512, 512, 512, FLAG_RES | FLAG_W32);
            ln_rows<<<M / 4, 256, 0, stream>>>(h32, ln2_w + i * 512, ln2_b + i * 512, abuf);
            gemm_f16<<<dim3(8, M / 128), 256, 0, stream>>>(
                abuf, wt_m1 + (size_t)i * 2048 * 512, mlp_b1 + i * 2048,
                nullptr, nullptr, bbuf, M, 2048, 512, 512, FLAG_W16 | FLAG_GELU);
            const int fl = FLAG_RES | FLAG_W32 | (i == 3 ? FLAG_W16 : 0);
            gemm_f16<<<dim3(2, M / 128), 256, 0, stream>>>(
                bbuf, wt_m2 + (size_t)i * 512 * 2048, mlp_b2 + i * 512,
                h32, h32, abuf, M, 512, 2048, 2048, fl);
        }

        // classifier: abuf viewed as (CH, 6144) f16; split-K via fp32 partials
        gemm_f16<<<dim3(2, CH / 128, 8), 256, 0, stream>>>(
            abuf, wt_c1, nullptr, nullptr, part1, nullptr, CH, 512, 6144, 768, FLAG_PART);
        skred_k<<<(CH * 512 + 255) / 256, 256, 0, stream>>>(
            part1, cls_b1, f1, CH * 512, 512, 8);
        gemm_f16<<<dim3(1, CH / 128, 4), 256, 0, stream>>>(
            f1, wt_c2, nullptr, nullptr, part2, nullptr, CH, 128, 512, 128, FLAG_PART);
        skcls_k<<<CH / 4, 256, 0, stream>>>(
            part2, cls_b2, cls_w3, cls_b3, (float*)d_out + (size_t)c * CH * 3, CH);
    }
}

// Round 2
// 3415.294 us; speedup vs baseline: 1.2310x; 1.2310x over previous
//
#include <hip/hip_runtime.h>
#include <cstdint>
#include <cstddef>

typedef _Float16 half8 __attribute__((ext_vector_type(8)));
typedef float floatx4 __attribute__((ext_vector_type(4)));

#define FLAG_RES  1
#define FLAG_GELU 2
#define FLAG_W32  4
#define FLAG_W16  8
#define FLAG_PART 16

// Fast exact-GELU: erf via Abramowitz-Stegun 7.1.26 (|err| <= 1.5e-7), __expf.
__device__ __forceinline__ float gelu_exact(float x) {
    const float z = fabsf(x) * 0.70710678118654752f;
    const float t = 1.f / fmaf(0.3275911f, z, 1.f);
    const float p = t * (0.254829592f + t * (-0.284496736f +
                     t * (1.421413741f + t * (-1.453152027f + t * 1.061405429f))));
    const float erfa = 1.f - p * __expf(-z * z);
    return 0.5f * x * (1.f + copysignf(erfa, x));
}

// ---------------------------------------------------------------------------
// GEMM: C(MxN) = A(MxK f16 rm) @ Bt(NxK f16 rm)^T + bias(fp32)
// 128x128 tile, BK=32, 256 thr (2x2 waves of 64x64). Register prefetch +
// LDS ping-pong, ONE barrier per iteration. LDS layout XOR-swizzled
// (16B chunk index ^= (row>>1)&3, applied on BOTH ds_write and ds_read)
// -> fragment ds_read_b128 is 2-way (free) instead of 8-way bank conflict.
// blockIdx.z = split-K slice of length klen (klen%32==0). FLAG_PART writes
// raw fp32 partials to out32 + z*M*N (no bias/act/res).
// ---------------------------------------------------------------------------
__global__ __launch_bounds__(256, 2) void gemm_f16(
    const _Float16* __restrict__ A, const _Float16* __restrict__ Bt,
    const float* __restrict__ bias, const float* __restrict__ resid,
    float* __restrict__ out32, _Float16* __restrict__ out16,
    int M, int N, int K, int klen, int flags)
{
    __shared__ __align__(16) _Float16 As[2][128 * 32];
    __shared__ __align__(16) _Float16 Bs[2][128 * 32];
    const int tid = threadIdx.x;
    const int wid = tid >> 6;
    const int lane = tid & 63;
    const int bm = blockIdx.y * 128;
    const int bn = blockIdx.x * 128;
    const int wr = wid >> 1, wc = wid & 1;
    const int lane15 = lane & 15, quad = lane >> 4;
    const int kb = blockIdx.z * klen;

    floatx4 acc[4][4];
#pragma unroll
    for (int i = 0; i < 4; i++)
#pragma unroll
        for (int j = 0; j < 4; j++)
            acc[i][j] = floatx4{0.f, 0.f, 0.f, 0.f};

    // staging map (per wave, 32 rows of A and Bt): lane l -> row l/4, chunk l%4
    const int r4 = lane >> 2;            // row within 16-row group
    const int ch = lane & 3;             // 16B chunk index
    const _Float16* Ap = A + ((size_t)bm + wid * 32 + r4) * K + kb + ch * 8;
    const _Float16* Bp = Bt + ((size_t)bn + wid * 32 + r4) * K + kb + ch * 8;
    const size_t row16 = (size_t)16 * K;
    // swizzled LDS write offset (halfs); rows r4 and r4+16 share swizzle bits
    const int lw = wid * 1024 + r4 * 32 + ((ch ^ ((r4 >> 1) & 3)) << 3);

    // fragment read offsets (halfs), swizzle-matched, loop-invariant
    int aoff[4], boff[4];
#pragma unroll
    for (int mi = 0; mi < 4; mi++)
        aoff[mi] = (wr * 64 + mi * 16 + lane15) * 32 +
                   ((quad ^ ((lane15 >> 1) & 3)) << 3);
#pragma unroll
    for (int ni = 0; ni < 4; ni++)
        boff[ni] = (wc * 64 + ni * 16 + lane15) * 32 +
                   ((quad ^ ((lane15 >> 1) & 3)) << 3);

    // prefetch tile 0 into registers
    int4 ra0 = *(const int4*)(Ap);
    int4 ra1 = *(const int4*)(Ap + row16);
    int4 rb0 = *(const int4*)(Bp);
    int4 rb1 = *(const int4*)(Bp + row16);

    const int nk = klen >> 5;
    for (int ik = 0; ik < nk; ik++) {
        _Float16* a_ = &As[ik & 1][0];
        _Float16* b_ = &Bs[ik & 1][0];
        *(int4*)(a_ + lw) = ra0;
        *(int4*)(a_ + lw + 512) = ra1;
        *(int4*)(b_ + lw) = rb0;
        *(int4*)(b_ + lw + 512) = rb1;
        __syncthreads();
        if (ik + 1 < nk) {                     // issue next-tile loads NOW;
            const int ko = (ik + 1) << 5;      // consumed at next ds_write
            ra0 = *(const int4*)(Ap + ko);
            ra1 = *(const int4*)(Ap + row16 + ko);
            rb0 = *(const int4*)(Bp + ko);
            rb1 = *(const int4*)(Bp + row16 + ko);
        }
        half8 af[4], bf[4];
#pragma unroll
        for (int mi = 0; mi < 4; mi++) af[mi] = *(const half8*)&a_[aoff[mi]];
#pragma unroll
        for (int ni = 0; ni < 4; ni++) bf[ni] = *(const half8*)&b_[boff[ni]];
#pragma unroll
        for (int mi = 0; mi < 4; mi++)
#pragma unroll
            for (int ni = 0; ni < 4; ni++)
                acc[mi][ni] = __builtin_amdgcn_mfma_f32_16x16x32_f16(
                    af[mi], bf[ni], acc[mi][ni], 0, 0, 0);
        // no trailing barrier: iter ik+1 writes the other LDS buffer, and the
        // barrier at ik+1 orders those writes after everyone's reads of ik.
    }

    // epilogue: C/D layout col = lane&15, row = quad*4 + reg
    if (flags & FLAG_PART) {
        float* po = out32 + (size_t)blockIdx.z * ((size_t)M * N);
#pragma unroll
        for (int mi = 0; mi < 4; mi++) {
            const int gmb = bm + wr * 64 + mi * 16 + quad * 4;
#pragma unroll
            for (int ni = 0; ni < 4; ni++) {
                const int gn = bn + wc * 64 + ni * 16 + lane15;
#pragma unroll
                for (int r = 0; r < 4; r++)
                    po[(size_t)(gmb + r) * N + gn] = acc[mi][ni][r];
            }
        }
        return;
    }
#pragma unroll
    for (int mi = 0; mi < 4; mi++) {
        const int gmb = bm + wr * 64 + mi * 16 + quad * 4;
#pragma unroll
        for (int ni = 0; ni < 4; ni++) {
            const int gn = bn + wc * 64 + ni * 16 + lane15;
            const float bv = bias[gn];
#pragma unroll
            for (int r = 0; r < 4; r++) {
                float v = acc[mi][ni][r] + bv;
                if (flags & FLAG_GELU) v = gelu_exact(v);
                const size_t off = (size_t)(gmb + r) * N + gn;
                if (flags & FLAG_RES) v += resid[off];
                if (flags & FLAG_W32) out32[off] = v;
                if (flags & FLAG_W16) out16[off] = (_Float16)v;
            }
        }
    }
}

// ---------------------------------------------------------------------------
// Split-K reduce: out[i] = gelu(bias[i%N] + sum_z part[z*MN + i]) as f16.
// ---------------------------------------------------------------------------
__global__ __launch_bounds__(256) void skred_k(
    const float* __restrict__ part, const float* __restrict__ bias,
    _Float16* __restrict__ out, int MN, int N, int S)
{
    const int i = blockIdx.x * 256 + threadIdx.x;
    if (i >= MN) return;
    float s = bias[i % N];
    for (int z = 0; z < S; z++) s += part[(size_t)z * MN + i];
    out[i] = (_Float16)gelu_exact(s);
}

// ---------------------------------------------------------------------------
// Fused split-K reduce (S=4, N=128) + gelu + final (128x3) matmul + bias.
// One wave per batch row; lanes hold 2 cols each; butterfly-reduce 3 dots.
// ---------------------------------------------------------------------------
__global__ __launch_bounds__(256) void skcls_k(
    const float* __restrict__ part, const float* __restrict__ b2,
    const float* __restrict__ w3, const float* __restrict__ b3,
    float* __restrict__ out, int CH)
{
    const int wid = threadIdx.x >> 6, lane = threadIdx.x & 63;
    const int b = blockIdx.x * 4 + wid;
    const size_t MN = (size_t)CH * 128;
    const int c0 = lane, c1 = lane + 64;
    float s0 = b2[c0], s1 = b2[c1];
#pragma unroll
    for (int z = 0; z < 4; z++) {
        s0 += part[z * MN + (size_t)b * 128 + c0];
        s1 += part[z * MN + (size_t)b * 128 + c1];
    }
    const float g0 = gelu_exact(s0), g1 = gelu_exact(s1);
    float a0 = g0 * w3[c0 * 3 + 0] + g1 * w3[c1 * 3 + 0];
    float a1 = g0 * w3[c0 * 3 + 1] + g1 * w3[c1 * 3 + 1];
    float a2 = g0 * w3[c0 * 3 + 2] + g1 * w3[c1 * 3 + 2];
#pragma unroll
    for (int m = 32; m >= 1; m >>= 1) {
        a0 += __shfl_xor(a0, m, 64);
        a1 += __shfl_xor(a1, m, 64);
        a2 += __shfl_xor(a2, m, 64);
    }
    if (lane == 0) {
        out[b * 3 + 0] = a0 + b3[0];
        out[b * 3 + 1] = a1 + b3[1];
        out[b * 3 + 2] = a2 + b3[2];
    }
}

// ---------------------------------------------------------------------------
// Row LayerNorm over 512 cols: fp32 in, fp32 params, f16 out. One wave/row.
// ---------------------------------------------------------------------------
__global__ __launch_bounds__(256) void ln_rows(
    const float* __restrict__ x, const float* __restrict__ w,
    const float* __restrict__ b, _Float16* __restrict__ out)
{
    const int wid = threadIdx.x >> 6, lane = threadIdx.x & 63;
    const size_t row = (size_t)blockIdx.x * 4 + wid;
    const int c0 = lane * 8;
    const float* xr = x + row * 512 + c0;
    float4 v0 = *(const float4*)xr;
    float4 v1 = *(const float4*)(xr + 4);
    float xv[8] = {v0.x, v0.y, v0.z, v0.w, v1.x, v1.y, v1.z, v1.w};
    float s = 0.f, q = 0.f;
#pragma unroll
    for (int j = 0; j < 8; j++) { s += xv[j]; q += xv[j] * xv[j]; }
#pragma unroll
    for (int m = 32; m >= 1; m >>= 1) {
        s += __shfl_xor(s, m, 64);
        q += __shfl_xor(q, m, 64);
    }
    const float mean = s * (1.f / 512.f);
    const float rstd = rsqrtf(q * (1.f / 512.f) - mean * mean + 1e-5f);
    half8 o;
#pragma unroll
    for (int j = 0; j < 8; j++)
        o[j] = (_Float16)((xv[j] - mean) * rstd * w[c0 + j] + b[c0 + j]);
    *(half8*)&out[row * 512 + c0] = o;
}

// ---------------------------------------------------------------------------
// Attention: 4 (b,head) units per 256-thread block (one wave each).
// qkv rows (1536): [q|k|v], head offset hd*64. f16 in/out.
// ---------------------------------------------------------------------------
__global__ __launch_bounds__(256) void attn_k(
    const _Float16* __restrict__ qkv, _Float16* __restrict__ o)
{
    __shared__ float qs[4][12][65], ks[4][12][65], vs[4][12][65];
    __shared__ float att[4][12][16];
    const int wid = threadIdx.x >> 6, lane = threadIdx.x & 63;
    const int unit = blockIdx.x * 4 + wid;
    const int b = unit >> 3, hd = unit & 7;
    const _Float16* base = qkv + (size_t)b * (12 * 1536) + hd * 64 + lane;
#pragma unroll
    for (int r = 0; r < 12; r++) {
        qs[wid][r][lane] = (float)base[r * 1536];
        ks[wid][r][lane] = (float)base[r * 1536 + 512];
        vs[wid][r][lane] = (float)base[r * 1536 + 1024];
    }
    __syncthreads();
#pragma unroll
    for (int i = 0; i < 3; i++) {
        const int p = lane + i * 64;
        if (p < 144) {
            const int qi = p / 12, kj = p - qi * 12;
            float d = 0.f;
            for (int e = 0; e < 64; e++) d += qs[wid][qi][e] * ks[wid][kj][e];
            att[wid][qi][kj] = d * 0.125f;   // 1/sqrt(64)
        }
    }
    __syncthreads();
    if (lane < 12) {
        float mx = att[wid][lane][0];
#pragma unroll
        for (int j = 1; j < 12; j++) mx = fmaxf(mx, att[wid][lane][j]);
        float ev[12], ssum = 0.f;
#pragma unroll
        for (int j = 0; j < 12; j++) { ev[j] = expf(att[wid][lane][j] - mx); ssum += ev[j]; }
        const float inv = 1.f / ssum;
#pragma unroll
        for (int j = 0; j < 12; j++) att[wid][lane][j] = ev[j] * inv;
    }
    __syncthreads();
    _Float16* ob = o + (size_t)b * (12 * 512) + hd * 64 + lane;
#pragma unroll
    for (int qi = 0; qi < 12; qi++) {
        float s = 0.f;
#pragma unroll
        for (int j = 0; j < 12; j++) s += att[wid][qi][j] * vs[wid][j][lane];
        ob[qi * 512] = (_Float16)s;
    }
}

// ---------------------------------------------------------------------------
// Fused factors + per-(batch,feature) time-norm -> (CH*12, 96) f16 patch rows.
// Two-pass recompute: pass1 accumulates stats, pass2 writes normalized f16.
// cl/vl in LDS are per-thread spill columns (no cross-thread sharing).
// ---------------------------------------------------------------------------
struct FSt { float e12, e26, ag, al, s1c, s2c, s1v; };

__device__ __forceinline__ void fderiv(
    int t, float c, float cprev, float co, float v, float vprev, float vo,
    FSt& s, float f[6])
{
    const float a12 = 2.f / 13.f, a26 = 2.f / 27.f, a14 = 1.f / 14.f;
    const float sv = v > 0.f ? v : 1.f;
    if (t > 0) {
        s.e12 = a12 * c + (1.f - a12) * s.e12;
        s.e26 = a26 * c + (1.f - a26) * s.e26;
    }
    const float macd = s.e12 - s.e26;
    const float delta = t > 0 ? c - cprev : 0.f;
    if (t > 0) {
        s.ag = a14 * fmaxf(delta, 0.f) + (1.f - a14) * s.ag;
        s.al = a14 * fmaxf(-delta, 0.f) + (1.f - a14) * s.al;
    }
    const float rs = s.ag / (s.al + 1e-10f);
    const float rsi = (100.f - 100.f / (1.f + rs)) * 0.01f;
    s.s1c += c; s.s2c += c * c; s.s1v += sv;
    if (t >= 20) {
        const float svo = vo > 0.f ? vo : 1.f;
        s.s1c -= co; s.s2c -= co * co; s.s1v -= svo;
    }
    float bb = 0.f, vmr = 1.f;
    if (t >= 19) {
        const float mean = s.s1c * 0.05f;
        const float sq = s.s2c * 0.05f;
        const float sd = sqrtf(fmaxf(sq - mean * mean, 0.f));
        bb = 4.f * sd / (mean + 1e-8f);
        vmr = sv / (s.s1v * 0.05f + 1e-8f);
    }
    float lr = 0.f, lv = 0.f;
    if (t > 0) {
        lr = logf(fmaxf(c, 1e-8f) / fmaxf(cprev, 1e-8f));
        const float svp = vprev > 0.f ? vprev : 1.f;
        lv = logf(sv / (svp + 1e-8f));
    }
    f[0] = isfinite(macd) ? macd : 0.f;
    f[1] = isfinite(rsi) ? rsi : 0.f;
    f[2] = isfinite(bb) ? bb : 0.f;
    f[3] = isfinite(lr) ? lr : 0.f;
    f[4] = isfinite(lv) ? lv : 0.f;
    f[5] = isfinite(vmr) ? vmr : 0.f;
}

__global__ __launch_bounds__(64) void factors_k(
    const float* __restrict__ x, const float* __restrict__ in_w,
    const float* __restrict__ in_b, _Float16* __restrict__ feats, int CH)
{
    const int tid = threadIdx.x;
    const int b = blockIdx.x * 64 + tid;
    if (b >= CH) return;
    __shared__ float cl[96][64];
    __shared__ float vl[96][64];
    const float* xb = x + (size_t)b * 480;

    float sum[11], ssq[11];
#pragma unroll
    for (int f = 0; f < 11; f++) { sum[f] = 0.f; ssq[f] = 0.f; }

    // stage close/vol + accumulate raw-col (f=0..4) stats in one pass
    for (int t = 0; t < 96; t++) {
        const float* xq = xb + t * 5;
        const float a0 = xq[0], a1 = xq[1], a2 = xq[2], c = xq[3], v = xq[4];
        cl[t][tid] = c; vl[t][tid] = v;
        sum[0] += a0; ssq[0] += a0 * a0;
        sum[1] += a1; ssq[1] += a1 * a1;
        sum[2] += a2; ssq[2] += a2 * a2;
        sum[3] += c;  ssq[3] += c * c;
        sum[4] += v;  ssq[4] += v * v;
    }

    // pass 1: derived-feature stats
    {
        const float c0 = cl[0][tid];
        FSt st{c0, c0, 0.f, 0.f, 0.f, 0.f, 0.f};
        for (int t = 0; t < 96; t++) {
            const float c = cl[t][tid], v = vl[t][tid];
            const float cp = t > 0 ? cl[t - 1][tid] : 0.f;
            const float vp = t > 0 ? vl[t - 1][tid] : 0.f;
            const float co = t >= 20 ? cl[t - 20][tid] : 0.f;
            const float vo = t >= 20 ? vl[t - 20][tid] : 0.f;
            float f6[6];
            fderiv(t, c, cp, co, v, vp, vo, st, f6);
#pragma unroll
            for (int j = 0; j < 6; j++) { sum[5 + j] += f6[j]; ssq[5 + j] += f6[j] * f6[j]; }
        }
    }
    float scale[11], shift[11];
#pragma unroll
    for (int f = 0; f < 11; f++) {
        const float m = sum[f] * (1.f / 96.f);
        const float var = ssq[f] * (1.f / 96.f) - m * m;
        const float r = rsqrtf(var + 1e-5f);
        scale[f] = r * in_w[f];
        shift[f] = in_b[f] - m * scale[f];
    }

    // pass 2: recompute, write normalized f16 patch rows + zero pad cols 88..95
    {
        const float c0 = cl[0][tid];
        FSt st{c0, c0, 0.f, 0.f, 0.f, 0.f, 0.f};
        _Float16* orow = feats + (size_t)b * 1152;
        for (int t = 0; t < 96; t++) {
            const float c = cl[t][tid], v = vl[t][tid];
            const float cp = t > 0 ? cl[t - 1][tid] : 0.f;
            const float vp = t > 0 ? vl[t - 1][tid] : 0.f;
            const float co = t >= 20 ? cl[t - 20][tid] : 0.f;
            const float vo = t >= 20 ? vl[t - 20][tid] : 0.f;
            float f6[6];
            fderiv(t, c, cp, co, v, vp, vo, st, f6);
            const float* xq = xb + t * 5;
            float o[11] = {xq[0], xq[1], xq[2], c, v, f6[0], f6[1], f6[2], f6[3], f6[4], f6[5]};
            _Float16* op = orow + (t >> 3) * 96 + (t & 7) * 11;
#pragma unroll
            for (int f = 0; f < 11; f++)
                op[f] = (_Float16)(o[f] * scale[f] + shift[f]);
        }
        const int4 z4 = {0, 0, 0, 0};
#pragma unroll
        for (int p = 0; p < 12; p++)
            *(int4*)(orow + p * 96 + 88) = z4;
    }
}

// ---------------------------------------------------------------------------
// Tiled transpose + cast, z-batched: W (K x N) fp32 -> Wt (N x Kpad) f16.
// ---------------------------------------------------------------------------
__global__ __launch_bounds__(256) void tr_k(
    const float* __restrict__ W, _Float16* __restrict__ Wt,
    int K, int N, int Kpad, long long ss, long long ds)
{
    W  += (size_t)blockIdx.z * ss;
    Wt += (size_t)blockIdx.z * ds;
    __shared__ _Float16 t[32][33];
    const int n0 = blockIdx.x * 32, k0 = blockIdx.y * 32;
#pragma unroll
    for (int j = 0; j < 4; j++) {
        const int k = k0 + threadIdx.y + j * 8;
        t[threadIdx.y + j * 8][threadIdx.x] =
            (k < K) ? (_Float16)W[(size_t)k * N + n0 + threadIdx.x] : (_Float16)0.f;
    }
    __syncthreads();
#pragma unroll
    for (int j = 0; j < 4; j++) {
        const int n = n0 + threadIdx.y + j * 8;
        Wt[(size_t)n * Kpad + k0 + threadIdx.x] = t[threadIdx.x][threadIdx.y + j * 8];
    }
}

// ---------------------------------------------------------------------------
extern "C" void kernel_launch(void* const* d_in, const int* in_sizes, int n_in,
                              void* d_out, int out_size, void* d_ws, size_t ws_size,
                              hipStream_t stream)
{
    static const int EXP[23] = {1966080, 11, 11, 45056, 512, 2048, 2048,
        3145728, 6144, 1048576, 2048, 2048, 2048, 4194304, 8192, 4194304, 2048,
        3145728, 512, 65536, 128, 384, 3};
    static const int S2D[23] = {18, 20, 22, 17, 19, 21, 2, 1, 6, 5, 12, 11,
        14, 16, 13, 15, 10, 9, 4, 3, 8, 7, 0};
    const void* in[23];
    if (n_in != 23 || out_size != 12288) return;
    bool ok = true;
    for (int i = 0; i < 23; i++) ok = ok && (in_sizes[i] == EXP[i]);
    if (ok) {
        for (int i = 0; i < 23; i++) in[i] = d_in[i];
    } else {
        bool ok2 = true;
        for (int s = 0; s < 23; s++) ok2 = ok2 && (in_sizes[s] == EXP[S2D[s]]);
        if (!ok2) return;
        for (int s = 0; s < 23; s++) in[S2D[s]] = d_in[s];
    }
    const float* x      = (const float*)in[0];
    const float* in_w   = (const float*)in[1];
    const float* in_b   = (const float*)in[2];
    const float* pe_w   = (const float*)in[3];
    const float* pe_b   = (const float*)in[4];
    const float* ln1_w  = (const float*)in[5];
    const float* ln1_b  = (const float*)in[6];
    const float* qkv_w  = (const float*)in[7];
    const float* qkv_b  = (const float*)in[8];
    const float* out_w  = (const float*)in[9];
    const float* out_b  = (const float*)in[10];
    const float* ln2_w  = (const float*)in[11];
    const float* ln2_b  = (const float*)in[12];
    const float* mlp_w1 = (const float*)in[13];
    const float* mlp_b1 = (const float*)in[14];
    const float* mlp_w2 = (const float*)in[15];
    const float* mlp_b2 = (const float*)in[16];
    const float* cls_w1 = (const float*)in[17];
    const float* cls_b1 = (const float*)in[18];
    const float* cls_w2 = (const float*)in[19];
    const float* cls_b2 = (const float*)in[20];
    const float* cls_w3 = (const float*)in[21];
    const float* cls_b3 = (const float*)in[22];

    // ---- f16 weight arena (~31.7 MB) ----
    char* ws = (char*)d_ws;
    size_t off = 0;
    _Float16* wt_pe  = (_Float16*)(ws + off); off += (size_t)512 * 96 * 2;
    _Float16* wt_qkv = (_Float16*)(ws + off); off += (size_t)4 * 1536 * 512 * 2;
    _Float16* wt_out = (_Float16*)(ws + off); off += (size_t)4 * 512 * 512 * 2;
    _Float16* wt_m1  = (_Float16*)(ws + off); off += (size_t)4 * 2048 * 512 * 2;
    _Float16* wt_m2  = (_Float16*)(ws + off); off += (size_t)4 * 512 * 2048 * 2;
    _Float16* wt_c1  = (_Float16*)(ws + off); off += (size_t)512 * 6144 * 2;
    _Float16* wt_c2  = (_Float16*)(ws + off); off += (size_t)128 * 512 * 2;
    const size_t wbytes = off;

    // adaptive chunk: per-batch bytes = h32 24576 + abuf 12288 + bbuf 49152
    const size_t per = 86016 + 64;
    int CH = 4096;
    while (CH > 128 && wbytes + (size_t)CH * per > ws_size) CH >>= 1;
    const int nch = 4096 / CH;
    const int M = CH * 12;

    float*    h32  = (float*)(ws + off);    off += (size_t)M * 512 * 4;
    _Float16* abuf = (_Float16*)(ws + off); off += (size_t)M * 512 * 2;
    _Float16* bbuf = (_Float16*)(ws + off); off += (size_t)M * 2048 * 2;

    _Float16* feats = bbuf;                 // dead after pe GEMM
    _Float16* f1 = (_Float16*)h32;          // classifier temp (h32 dead then)
    float* part1 = (float*)bbuf;                          // 8*CH*512 fp32
    float* part2 = part1 + (size_t)8 * CH * 512;          // 4*CH*128 fp32

    // ---- weight prep: fp32 (K,N) -> f16 (N,Kpad) transposed, z-batched ----
    tr_k<<<dim3(16, 3, 1),   dim3(32, 8), 0, stream>>>(pe_w, wt_pe, 88, 512, 96, 0, 0);
    tr_k<<<dim3(48, 16, 4),  dim3(32, 8), 0, stream>>>(qkv_w, wt_qkv, 512, 1536, 512,
        (long long)512 * 1536, (long long)1536 * 512);
    tr_k<<<dim3(16, 16, 4),  dim3(32, 8), 0, stream>>>(out_w, wt_out, 512, 512, 512,
        (long long)512 * 512, (long long)512 * 512);
    tr_k<<<dim3(64, 16, 4),  dim3(32, 8), 0, stream>>>(mlp_w1, wt_m1, 512, 2048, 512,
        (long long)512 * 2048, (long long)2048 * 512);
    tr_k<<<dim3(16, 64, 4),  dim3(32, 8), 0, stream>>>(mlp_w2, wt_m2, 2048, 512, 2048,
        (long long)2048 * 512, (long long)512 * 2048);
    tr_k<<<dim3(16, 192, 1), dim3(32, 8), 0, stream>>>(cls_w1, wt_c1, 6144, 512, 6144, 0, 0);
    tr_k<<<dim3(4, 16, 1),   dim3(32, 8), 0, stream>>>(cls_w2, wt_c2, 512, 128, 512, 0, 0);

    for (int c = 0; c < nch; c++) {
        const float* xc = x + (size_t)c * CH * 480;
        factors_k<<<CH / 64, 64, 0, stream>>>(xc, in_w, in_b, feats, CH);
        gemm_f16<<<dim3(4, M / 128), 256, 0, stream>>>(
            feats, wt_pe, pe_b, nullptr, h32, nullptr, M, 512, 96, 96, FLAG_W32);

        for (int i = 0; i < 4; i++) {
            ln_rows<<<M / 4, 256, 0, stream>>>(h32, ln1_w + i * 512, ln1_b + i * 512, abuf);
            gemm_f16<<<dim3(12, M / 128), 256, 0, stream>>>(
                abuf, wt_qkv + (size_t)i * 1536 * 512, qkv_b + i * 1536,
                nullptr, nullptr, bbuf, M, 1536, 512, 512, FLAG_W16);
            attn_k<<<CH * 2, 256, 0, stream>>>(bbuf, abuf);
            gemm_f16<<<dim3(4, M / 128), 256, 0, stream>>>(
                abuf, wt_out + (size_t)i * 512 * 512, out_b + i * 512,
                h32, h32, nullptr, M, 512, 512, 512, FLAG_RES | FLAG_W32);
            ln_rows<<<M / 4, 256, 0, stream>>>(h32, ln2_w + i * 512, ln2_b + i * 512, abuf);
            gemm_f16<<<dim3(16, M / 128), 256, 0, stream>>>(
                abuf, wt_m1 + (size_t)i * 2048 * 512, mlp_b1 + i * 2048,
                nullptr, nullptr, bbuf, M, 2048, 512, 512, FLAG_W16 | FLAG_GELU);
            // at i==3 the fp32 residual stream is dead afterwards -> skip the
            // 100 MB h32 write-back, emit only the f16 abuf the classifier reads
            const int fl = FLAG_RES | (i == 3 ? FLAG_W16 : FLAG_W32);
            gemm_f16<<<dim3(4, M / 128), 256, 0, stream>>>(
                bbuf, wt_m2 + (size_t)i * 512 * 2048, mlp_b2 + i * 512,
                h32, h32, abuf, M, 512, 2048, 2048, fl);
        }

        // classifier: abuf viewed as (CH, 6144) f16; split-K via fp32 partials
        gemm_f16<<<dim3(4, CH / 128, 8), 256, 0, stream>>>(
            abuf, wt_c1, nullptr, nullptr, part1, nullptr, CH, 512, 6144, 768, FLAG_PART);
        skred_k<<<(CH * 512 + 255) / 256, 256, 0, stream>>>(
            part1, cls_b1, f1, CH * 512, 512, 8);
        gemm_f16<<<dim3(1, CH / 128, 4), 256, 0, stream>>>(
            f1, wt_c2, nullptr, nullptr, part2, nullptr, CH, 128, 512, 128, FLAG_PART);
        skcls_k<<<CH / 4, 256, 0, stream>>>(
            part2, cls_b2, cls_w3, cls_b3, (float*)d_out + (size_t)c * CH * 3, CH);
    }
}

// Round 3
// 3365.253 us; speedup vs baseline: 1.2493x; 1.0149x over previous
//
#include <hip/hip_runtime.h>
#include <cstdint>
#include <cstddef>

typedef _Float16 half8 __attribute__((ext_vector_type(8)));
typedef float floatx4 __attribute__((ext_vector_type(4)));

#define FLAG_RES  1
#define FLAG_GELU 2
#define FLAG_W32  4
#define FLAG_W16  8
#define FLAG_PART 16

// Fast exact-GELU: erf via Abramowitz-Stegun 7.1.26 (|err| <= 1.5e-7), __expf.
__device__ __forceinline__ float gelu_exact(float x) {
    const float z = fabsf(x) * 0.70710678118654752f;
    const float t = 1.f / fmaf(0.3275911f, z, 1.f);
    const float p = t * (0.254829592f + t * (-0.284496736f +
                     t * (1.421413741f + t * (-1.453152027f + t * 1.061405429f))));
    const float erfa = 1.f - p * __expf(-z * z);
    return 0.5f * x * (1.f + copysignf(erfa, x));
}

// ---------------------------------------------------------------------------
// GEMM: C(MxN) = A(MxK f16 rm) @ Bt(NxK f16 rm)^T + bias(fp32)
// 128x128 tile, BK=32, 256 thr (2x2 waves of 64x64). Register prefetch +
// LDS ping-pong, ONE barrier per iteration. LDS layout XOR-swizzled
// (16B chunk index ^= (row>>1)&3, on BOTH ds_write and ds_read) -> fragment
// ds_read_b128 is 2-way (free) instead of 8-way bank conflict [verified r2:
// SQ_LDS_BANK_CONFLICT 6.3M -> 0].
// blockIdx.z = split-K slice of length klen (klen%32==0). FLAG_PART writes
// raw fp32 partials to out32 + z*M*N (no bias/act/res).
// ---------------------------------------------------------------------------
__global__ __launch_bounds__(256, 2) void gemm_f16(
    const _Float16* __restrict__ A, const _Float16* __restrict__ Bt,
    const float* __restrict__ bias, const float* __restrict__ resid,
    float* __restrict__ out32, _Float16* __restrict__ out16,
    int M, int N, int K, int klen, int flags)
{
    __shared__ __align__(16) _Float16 As[2][128 * 32];
    __shared__ __align__(16) _Float16 Bs[2][128 * 32];
    const int tid = threadIdx.x;
    const int wid = tid >> 6;
    const int lane = tid & 63;
    const int bm = blockIdx.y * 128;
    const int bn = blockIdx.x * 128;
    const int wr = wid >> 1, wc = wid & 1;
    const int lane15 = lane & 15, quad = lane >> 4;
    const int kb = blockIdx.z * klen;

    floatx4 acc[4][4];
#pragma unroll
    for (int i = 0; i < 4; i++)
#pragma unroll
        for (int j = 0; j < 4; j++)
            acc[i][j] = floatx4{0.f, 0.f, 0.f, 0.f};

    // staging map (per wave, 32 rows of A and Bt): lane l -> row l/4, chunk l%4
    const int r4 = lane >> 2;            // row within 16-row group
    const int ch = lane & 3;             // 16B chunk index
    const _Float16* Ap = A + ((size_t)bm + wid * 32 + r4) * K + kb + ch * 8;
    const _Float16* Bp = Bt + ((size_t)bn + wid * 32 + r4) * K + kb + ch * 8;
    const size_t row16 = (size_t)16 * K;
    // swizzled LDS write offset (halfs); rows r4 and r4+16 share swizzle bits
    const int lw = wid * 1024 + r4 * 32 + ((ch ^ ((r4 >> 1) & 3)) << 3);

    // fragment read offsets (halfs), swizzle-matched, loop-invariant
    int aoff[4], boff[4];
#pragma unroll
    for (int mi = 0; mi < 4; mi++)
        aoff[mi] = (wr * 64 + mi * 16 + lane15) * 32 +
                   ((quad ^ ((lane15 >> 1) & 3)) << 3);
#pragma unroll
    for (int ni = 0; ni < 4; ni++)
        boff[ni] = (wc * 64 + ni * 16 + lane15) * 32 +
                   ((quad ^ ((lane15 >> 1) & 3)) << 3);

    // prefetch tile 0 into registers
    int4 ra0 = *(const int4*)(Ap);
    int4 ra1 = *(const int4*)(Ap + row16);
    int4 rb0 = *(const int4*)(Bp);
    int4 rb1 = *(const int4*)(Bp + row16);

    const int nk = klen >> 5;
    for (int ik = 0; ik < nk; ik++) {
        _Float16* a_ = &As[ik & 1][0];
        _Float16* b_ = &Bs[ik & 1][0];
        *(int4*)(a_ + lw) = ra0;
        *(int4*)(a_ + lw + 512) = ra1;
        *(int4*)(b_ + lw) = rb0;
        *(int4*)(b_ + lw + 512) = rb1;
        __syncthreads();
        if (ik + 1 < nk) {                     // issue next-tile loads NOW;
            const int ko = (ik + 1) << 5;      // consumed at next ds_write
            ra0 = *(const int4*)(Ap + ko);
            ra1 = *(const int4*)(Ap + row16 + ko);
            rb0 = *(const int4*)(Bp + ko);
            rb1 = *(const int4*)(Bp + row16 + ko);
        }
        half8 af[4], bf[4];
#pragma unroll
        for (int mi = 0; mi < 4; mi++) af[mi] = *(const half8*)&a_[aoff[mi]];
#pragma unroll
        for (int ni = 0; ni < 4; ni++) bf[ni] = *(const half8*)&b_[boff[ni]];
#pragma unroll
        for (int mi = 0; mi < 4; mi++)
#pragma unroll
            for (int ni = 0; ni < 4; ni++)
                acc[mi][ni] = __builtin_amdgcn_mfma_f32_16x16x32_f16(
                    af[mi], bf[ni], acc[mi][ni], 0, 0, 0);
        // no trailing barrier: iter ik+1 writes the other LDS buffer, and the
        // barrier at ik+1 orders those writes after everyone's reads of ik.
    }

    // epilogue: C/D layout col = lane&15, row = quad*4 + reg
    if (flags & FLAG_PART) {
        float* po = out32 + (size_t)blockIdx.z * ((size_t)M * N);
#pragma unroll
        for (int mi = 0; mi < 4; mi++) {
            const int gmb = bm + wr * 64 + mi * 16 + quad * 4;
#pragma unroll
            for (int ni = 0; ni < 4; ni++) {
                const int gn = bn + wc * 64 + ni * 16 + lane15;
#pragma unroll
                for (int r = 0; r < 4; r++)
                    po[(size_t)(gmb + r) * N + gn] = acc[mi][ni][r];
            }
        }
        return;
    }
#pragma unroll
    for (int mi = 0; mi < 4; mi++) {
        const int gmb = bm + wr * 64 + mi * 16 + quad * 4;
#pragma unroll
        for (int ni = 0; ni < 4; ni++) {
            const int gn = bn + wc * 64 + ni * 16 + lane15;
            const float bv = bias[gn];
#pragma unroll
            for (int r = 0; r < 4; r++) {
                float v = acc[mi][ni][r] + bv;
                if (flags & FLAG_GELU) v = gelu_exact(v);
                const size_t off = (size_t)(gmb + r) * N + gn;
                if (flags & FLAG_RES) v += resid[off];
                if (flags & FLAG_W32) out32[off] = v;
                if (flags & FLAG_W16) out16[off] = (_Float16)v;
            }
        }
    }
}

// ---------------------------------------------------------------------------
// Split-K reduce: out[i] = gelu(bias[i%N] + sum_z part[z*MN + i]) as f16.
// ---------------------------------------------------------------------------
__global__ __launch_bounds__(256) void skred_k(
    const float* __restrict__ part, const float* __restrict__ bias,
    _Float16* __restrict__ out, int MN, int N, int S)
{
    const int i = blockIdx.x * 256 + threadIdx.x;
    if (i >= MN) return;
    float s = bias[i % N];
    for (int z = 0; z < S; z++) s += part[(size_t)z * MN + i];
    out[i] = (_Float16)gelu_exact(s);
}

// ---------------------------------------------------------------------------
// Fused split-K reduce (S=4, N=128) + gelu + final (128x3) matmul + bias.
// One wave per batch row; lanes hold 2 cols each; butterfly-reduce 3 dots.
// ---------------------------------------------------------------------------
__global__ __launch_bounds__(256) void skcls_k(
    const float* __restrict__ part, const float* __restrict__ b2,
    const float* __restrict__ w3, const float* __restrict__ b3,
    float* __restrict__ out, int CH)
{
    const int wid = threadIdx.x >> 6, lane = threadIdx.x & 63;
    const int b = blockIdx.x * 4 + wid;
    const size_t MN = (size_t)CH * 128;
    const int c0 = lane, c1 = lane + 64;
    float s0 = b2[c0], s1 = b2[c1];
#pragma unroll
    for (int z = 0; z < 4; z++) {
        s0 += part[z * MN + (size_t)b * 128 + c0];
        s1 += part[z * MN + (size_t)b * 128 + c1];
    }
    const float g0 = gelu_exact(s0), g1 = gelu_exact(s1);
    float a0 = g0 * w3[c0 * 3 + 0] + g1 * w3[c1 * 3 + 0];
    float a1 = g0 * w3[c0 * 3 + 1] + g1 * w3[c1 * 3 + 1];
    float a2 = g0 * w3[c0 * 3 + 2] + g1 * w3[c1 * 3 + 2];
#pragma unroll
    for (int m = 32; m >= 1; m >>= 1) {
        a0 += __shfl_xor(a0, m, 64);
        a1 += __shfl_xor(a1, m, 64);
        a2 += __shfl_xor(a2, m, 64);
    }
    if (lane == 0) {
        out[b * 3 + 0] = a0 + b3[0];
        out[b * 3 + 1] = a1 + b3[1];
        out[b * 3 + 2] = a2 + b3[2];
    }
}

// ---------------------------------------------------------------------------
// Row LayerNorm over 512 cols: fp32 in, fp32 params, f16 out. One wave/row.
// ---------------------------------------------------------------------------
__global__ __launch_bounds__(256) void ln_rows(
    const float* __restrict__ x, const float* __restrict__ w,
    const float* __restrict__ b, _Float16* __restrict__ out)
{
    const int wid = threadIdx.x >> 6, lane = threadIdx.x & 63;
    const size_t row = (size_t)blockIdx.x * 4 + wid;
    const int c0 = lane * 8;
    const float* xr = x + row * 512 + c0;
    float4 v0 = *(const float4*)xr;
    float4 v1 = *(const float4*)(xr + 4);
    float xv[8] = {v0.x, v0.y, v0.z, v0.w, v1.x, v1.y, v1.z, v1.w};
    float s = 0.f, q = 0.f;
#pragma unroll
    for (int j = 0; j < 8; j++) { s += xv[j]; q += xv[j] * xv[j]; }
#pragma unroll
    for (int m = 32; m >= 1; m >>= 1) {
        s += __shfl_xor(s, m, 64);
        q += __shfl_xor(q, m, 64);
    }
    const float mean = s * (1.f / 512.f);
    const float rstd = rsqrtf(q * (1.f / 512.f) - mean * mean + 1e-5f);
    half8 o;
#pragma unroll
    for (int j = 0; j < 8; j++)
        o[j] = (_Float16)((xv[j] - mean) * rstd * w[c0 + j] + b[c0 + j]);
    *(half8*)&out[row * 512 + c0] = o;
}

// ---------------------------------------------------------------------------
// Attention: 4 (b,head) units per 256-thread block (one wave each).
// qkv rows (1536): [q|k|v], head offset hd*64. f16 in/out.
// ---------------------------------------------------------------------------
__global__ __launch_bounds__(256) void attn_k(
    const _Float16* __restrict__ qkv, _Float16* __restrict__ o)
{
    __shared__ float qs[4][12][65], ks[4][12][65], vs[4][12][65];
    __shared__ float att[4][12][16];
    const int wid = threadIdx.x >> 6, lane = threadIdx.x & 63;
    const int unit = blockIdx.x * 4 + wid;
    const int b = unit >> 3, hd = unit & 7;
    const _Float16* base = qkv + (size_t)b * (12 * 1536) + hd * 64 + lane;
#pragma unroll
    for (int r = 0; r < 12; r++) {
        qs[wid][r][lane] = (float)base[r * 1536];
        ks[wid][r][lane] = (float)base[r * 1536 + 512];
        vs[wid][r][lane] = (float)base[r * 1536 + 1024];
    }
    __syncthreads();
#pragma unroll
    for (int i = 0; i < 3; i++) {
        const int p = lane + i * 64;
        if (p < 144) {
            const int qi = p / 12, kj = p - qi * 12;
            float d = 0.f;
            for (int e = 0; e < 64; e++) d += qs[wid][qi][e] * ks[wid][kj][e];
            att[wid][qi][kj] = d * 0.125f;   // 1/sqrt(64)
        }
    }
    __syncthreads();
    if (lane < 12) {
        float mx = att[wid][lane][0];
#pragma unroll
        for (int j = 1; j < 12; j++) mx = fmaxf(mx, att[wid][lane][j]);
        float ev[12], ssum = 0.f;
#pragma unroll
        for (int j = 0; j < 12; j++) { ev[j] = expf(att[wid][lane][j] - mx); ssum += ev[j]; }
        const float inv = 1.f / ssum;
#pragma unroll
        for (int j = 0; j < 12; j++) att[wid][lane][j] = ev[j] * inv;
    }
    __syncthreads();
    _Float16* ob = o + (size_t)b * (12 * 512) + hd * 64 + lane;
#pragma unroll
    for (int qi = 0; qi < 12; qi++) {
        float s = 0.f;
#pragma unroll
        for (int j = 0; j < 12; j++) s += att[wid][qi][j] * vs[wid][j][lane];
        ob[qi * 512] = (_Float16)s;
    }
}

// ---------------------------------------------------------------------------
// Fused factors + per-(batch,feature) time-norm -> (CH*12, 96) f16 patch rows.
// Two-pass recompute: pass1 accumulates stats, pass2 writes normalized f16.
// cl/vl in LDS are per-thread spill columns (no cross-thread sharing).
// ---------------------------------------------------------------------------
struct FSt { float e12, e26, ag, al, s1c, s2c, s1v; };

__device__ __forceinline__ void fderiv(
    int t, float c, float cprev, float co, float v, float vprev, float vo,
    FSt& s, float f[6])
{
    const float a12 = 2.f / 13.f, a26 = 2.f / 27.f, a14 = 1.f / 14.f;
    const float sv = v > 0.f ? v : 1.f;
    if (t > 0) {
        s.e12 = a12 * c + (1.f - a12) * s.e12;
        s.e26 = a26 * c + (1.f - a26) * s.e26;
    }
    const float macd = s.e12 - s.e26;
    const float delta = t > 0 ? c - cprev : 0.f;
    if (t > 0) {
        s.ag = a14 * fmaxf(delta, 0.f) + (1.f - a14) * s.ag;
        s.al = a14 * fmaxf(-delta, 0.f) + (1.f - a14) * s.al;
    }
    const float rs = s.ag / (s.al + 1e-10f);
    const float rsi = (100.f - 100.f / (1.f + rs)) * 0.01f;
    s.s1c += c; s.s2c += c * c; s.s1v += sv;
    if (t >= 20) {
        const float svo = vo > 0.f ? vo : 1.f;
        s.s1c -= co; s.s2c -= co * co; s.s1v -= svo;
    }
    float bb = 0.f, vmr = 1.f;
    if (t >= 19) {
        const float mean = s.s1c * 0.05f;
        const float sq = s.s2c * 0.05f;
        const float sd = sqrtf(fmaxf(sq - mean * mean, 0.f));
        bb = 4.f * sd / (mean + 1e-8f);
        vmr = sv / (s.s1v * 0.05f + 1e-8f);
    }
    float lr = 0.f, lv = 0.f;
    if (t > 0) {
        lr = logf(fmaxf(c, 1e-8f) / fmaxf(cprev, 1e-8f));
        const float svp = vprev > 0.f ? vprev : 1.f;
        lv = logf(sv / (svp + 1e-8f));
    }
    f[0] = isfinite(macd) ? macd : 0.f;
    f[1] = isfinite(rsi) ? rsi : 0.f;
    f[2] = isfinite(bb) ? bb : 0.f;
    f[3] = isfinite(lr) ? lr : 0.f;
    f[4] = isfinite(lv) ? lv : 0.f;
    f[5] = isfinite(vmr) ? vmr : 0.f;
}

__global__ __launch_bounds__(64) void factors_k(
    const float* __restrict__ x, const float* __restrict__ in_w,
    const float* __restrict__ in_b, _Float16* __restrict__ feats, int CH)
{
    const int tid = threadIdx.x;
    const int b = blockIdx.x * 64 + tid;
    if (b >= CH) return;
    __shared__ float cl[96][64];
    __shared__ float vl[96][64];
    const float* xb = x + (size_t)b * 480;

    float sum[11], ssq[11];
#pragma unroll
    for (int f = 0; f < 11; f++) { sum[f] = 0.f; ssq[f] = 0.f; }

    // stage close/vol + accumulate raw-col (f=0..4) stats in one pass
    for (int t = 0; t < 96; t++) {
        const float* xq = xb + t * 5;
        const float a0 = xq[0], a1 = xq[1], a2 = xq[2], c = xq[3], v = xq[4];
        cl[t][tid] = c; vl[t][tid] = v;
        sum[0] += a0; ssq[0] += a0 * a0;
        sum[1] += a1; ssq[1] += a1 * a1;
        sum[2] += a2; ssq[2] += a2 * a2;
        sum[3] += c;  ssq[3] += c * c;
        sum[4] += v;  ssq[4] += v * v;
    }

    // pass 1: derived-feature stats
    {
        const float c0 = cl[0][tid];
        FSt st{c0, c0, 0.f, 0.f, 0.f, 0.f, 0.f};
        for (int t = 0; t < 96; t++) {
            const float c = cl[t][tid], v = vl[t][tid];
            const float cp = t > 0 ? cl[t - 1][tid] : 0.f;
            const float vp = t > 0 ? vl[t - 1][tid] : 0.f;
            const float co = t >= 20 ? cl[t - 20][tid] : 0.f;
            const float vo = t >= 20 ? vl[t - 20][tid] : 0.f;
            float f6[6];
            fderiv(t, c, cp, co, v, vp, vo, st, f6);
#pragma unroll
            for (int j = 0; j < 6; j++) { sum[5 + j] += f6[j]; ssq[5 + j] += f6[j] * f6[j]; }
        }
    }
    float scale[11], shift[11];
#pragma unroll
    for (int f = 0; f < 11; f++) {
        const float m = sum[f] * (1.f / 96.f);
        const float var = ssq[f] * (1.f / 96.f) - m * m;
        const float r = rsqrtf(var + 1e-5f);
        scale[f] = r * in_w[f];
        shift[f] = in_b[f] - m * scale[f];
    }

    // pass 2: recompute, write normalized f16 patch rows + zero pad cols 88..95
    {
        const float c0 = cl[0][tid];
        FSt st{c0, c0, 0.f, 0.f, 0.f, 0.f, 0.f};
        _Float16* orow = feats + (size_t)b * 1152;
        for (int t = 0; t < 96; t++) {
            const float c = cl[t][tid], v = vl[t][tid];
            const float cp = t > 0 ? cl[t - 1][tid] : 0.f;
            const float vp = t > 0 ? vl[t - 1][tid] : 0.f;
            const float co = t >= 20 ? cl[t - 20][tid] : 0.f;
            const float vo = t >= 20 ? vl[t - 20][tid] : 0.f;
            float f6[6];
            fderiv(t, c, cp, co, v, vp, vo, st, f6);
            const float* xq = xb + t * 5;
            float o[11] = {xq[0], xq[1], xq[2], c, v, f6[0], f6[1], f6[2], f6[3], f6[4], f6[5]};
            _Float16* op = orow + (t >> 3) * 96 + (t & 7) * 11;
#pragma unroll
            for (int f = 0; f < 11; f++)
                op[f] = (_Float16)(o[f] * scale[f] + shift[f]);
        }
        const int4 z4 = {0, 0, 0, 0};
#pragma unroll
        for (int p = 0; p < 12; p++)
            *(int4*)(orow + p * 96 + 88) = z4;
    }
}

// ---------------------------------------------------------------------------
// Tiled transpose + cast, z-batched: W (K x N) fp32 -> Wt (N x Kpad) f16.
// ---------------------------------------------------------------------------
__global__ __launch_bounds__(256) void tr_k(
    const float* __restrict__ W, _Float16* __restrict__ Wt,
    int K, int N, int Kpad, long long ss, long long ds)
{
    W  += (size_t)blockIdx.z * ss;
    Wt += (size_t)blockIdx.z * ds;
    __shared__ _Float16 t[32][33];
    const int n0 = blockIdx.x * 32, k0 = blockIdx.y * 32;
#pragma unroll
    for (int j = 0; j < 4; j++) {
        const int k = k0 + threadIdx.y + j * 8;
        t[threadIdx.y + j * 8][threadIdx.x] =
            (k < K) ? (_Float16)W[(size_t)k * N + n0 + threadIdx.x] : (_Float16)0.f;
    }
    __syncthreads();
#pragma unroll
    for (int j = 0; j < 4; j++) {
        const int n = n0 + threadIdx.y + j * 8;
        Wt[(size_t)n * Kpad + k0 + threadIdx.x] = t[threadIdx.x][threadIdx.y + j * 8];
    }
}

// ---------------------------------------------------------------------------
extern "C" void kernel_launch(void* const* d_in, const int* in_sizes, int n_in,
                              void* d_out, int out_size, void* d_ws, size_t ws_size,
                              hipStream_t stream)
{
    static const int EXP[23] = {1966080, 11, 11, 45056, 512, 2048, 2048,
        3145728, 6144, 1048576, 2048, 2048, 2048, 4194304, 8192, 4194304, 2048,
        3145728, 512, 65536, 128, 384, 3};
    static const int S2D[23] = {18, 20, 22, 17, 19, 21, 2, 1, 6, 5, 12, 11,
        14, 16, 13, 15, 10, 9, 4, 3, 8, 7, 0};
    const void* in[23];
    if (n_in != 23 || out_size != 12288) return;
    bool ok = true;
    for (int i = 0; i < 23; i++) ok = ok && (in_sizes[i] == EXP[i]);
    if (ok) {
        for (int i = 0; i < 23; i++) in[i] = d_in[i];
    } else {
        bool ok2 = true;
        for (int s = 0; s < 23; s++) ok2 = ok2 && (in_sizes[s] == EXP[S2D[s]]);
        if (!ok2) return;
        for (int s = 0; s < 23; s++) in[S2D[s]] = d_in[s];
    }
    const float* x      = (const float*)in[0];
    const float* in_w   = (const float*)in[1];
    const float* in_b   = (const float*)in[2];
    const float* pe_w   = (const float*)in[3];
    const float* pe_b   = (const float*)in[4];
    const float* ln1_w  = (const float*)in[5];
    const float* ln1_b  = (const float*)in[6];
    const float* qkv_w  = (const float*)in[7];
    const float* qkv_b  = (const float*)in[8];
    const float* out_w  = (const float*)in[9];
    const float* out_b  = (const float*)in[10];
    const float* ln2_w  = (const float*)in[11];
    const float* ln2_b  = (const float*)in[12];
    const float* mlp_w1 = (const float*)in[13];
    const float* mlp_b1 = (const float*)in[14];
    const float* mlp_w2 = (const float*)in[15];
    const float* mlp_b2 = (const float*)in[16];
    const float* cls_w1 = (const float*)in[17];
    const float* cls_b1 = (const float*)in[18];
    const float* cls_w2 = (const float*)in[19];
    const float* cls_b2 = (const float*)in[20];
    const float* cls_w3 = (const float*)in[21];
    const float* cls_b3 = (const float*)in[22];

    // ---- f16 weight arena (~31.7 MB) ----
    char* ws = (char*)d_ws;
    size_t off = 0;
    _Float16* wt_pe  = (_Float16*)(ws + off); off += (size_t)512 * 96 * 2;
    _Float16* wt_qkv = (_Float16*)(ws + off); off += (size_t)4 * 1536 * 512 * 2;
    _Float16* wt_out = (_Float16*)(ws + off); off += (size_t)4 * 512 * 512 * 2;
    _Float16* wt_m1  = (_Float16*)(ws + off); off += (size_t)4 * 2048 * 512 * 2;
    _Float16* wt_m2  = (_Float16*)(ws + off); off += (size_t)4 * 512 * 2048 * 2;
    _Float16* wt_c1  = (_Float16*)(ws + off); off += (size_t)512 * 6144 * 2;
    _Float16* wt_c2  = (_Float16*)(ws + off); off += (size_t)128 * 512 * 2;
    const size_t wbytes = off;

    // LLC-blocking: cap chunk at 2048 so the per-chunk working set
    // (h32 50 MB + bbuf 100 MB + abuf 25 MB + weights 32 MB ~ 207 MB)
    // stays inside the 256 MB Infinity Cache -> the fp32 residual stream
    // (the FETCH~100/WRITE~100 MB signature on the hot dispatches) stops
    // round-tripping HBM. per-batch bytes = h32 24576 + abuf 12288 + bbuf 49152
    const size_t per = 86016 + 64;
    int CH = 2048;
    while (CH > 128 && wbytes + (size_t)CH * per > ws_size) CH >>= 1;
    const int nch = 4096 / CH;
    const int M = CH * 12;

    float*    h32  = (float*)(ws + off);    off += (size_t)M * 512 * 4;
    _Float16* abuf = (_Float16*)(ws + off); off += (size_t)M * 512 * 2;
    _Float16* bbuf = (_Float16*)(ws + off); off += (size_t)M * 2048 * 2;

    _Float16* feats = bbuf;                 // dead after pe GEMM
    _Float16* f1 = (_Float16*)h32;          // classifier temp (h32 dead then)
    float* part1 = (float*)bbuf;                          // 8*CH*512 fp32
    float* part2 = part1 + (size_t)8 * CH * 512;          // 4*CH*128 fp32

    // ---- weight prep: fp32 (K,N) -> f16 (N,Kpad) transposed, z-batched ----
    tr_k<<<dim3(16, 3, 1),   dim3(32, 8), 0, stream>>>(pe_w, wt_pe, 88, 512, 96, 0, 0);
    tr_k<<<dim3(48, 16, 4),  dim3(32, 8), 0, stream>>>(qkv_w, wt_qkv, 512, 1536, 512,
        (long long)512 * 1536, (long long)1536 * 512);
    tr_k<<<dim3(16, 16, 4),  dim3(32, 8), 0, stream>>>(out_w, wt_out, 512, 512, 512,
        (long long)512 * 512, (long long)512 * 512);
    tr_k<<<dim3(64, 16, 4),  dim3(32, 8), 0, stream>>>(mlp_w1, wt_m1, 512, 2048, 512,
        (long long)512 * 2048, (long long)2048 * 512);
    tr_k<<<dim3(16, 64, 4),  dim3(32, 8), 0, stream>>>(mlp_w2, wt_m2, 2048, 512, 2048,
        (long long)2048 * 512, (long long)512 * 2048);
    tr_k<<<dim3(16, 192, 1), dim3(32, 8), 0, stream>>>(cls_w1, wt_c1, 6144, 512, 6144, 0, 0);
    tr_k<<<dim3(4, 16, 1),   dim3(32, 8), 0, stream>>>(cls_w2, wt_c2, 512, 128, 512, 0, 0);

    for (int c = 0; c < nch; c++) {
        const float* xc = x + (size_t)c * CH * 480;
        factors_k<<<CH / 64, 64, 0, stream>>>(xc, in_w, in_b, feats, CH);
        gemm_f16<<<dim3(4, M / 128), 256, 0, stream>>>(
            feats, wt_pe, pe_b, nullptr, h32, nullptr, M, 512, 96, 96, FLAG_W32);

        for (int i = 0; i < 4; i++) {
            ln_rows<<<M / 4, 256, 0, stream>>>(h32, ln1_w + i * 512, ln1_b + i * 512, abuf);
            gemm_f16<<<dim3(12, M / 128), 256, 0, stream>>>(
                abuf, wt_qkv + (size_t)i * 1536 * 512, qkv_b + i * 1536,
                nullptr, nullptr, bbuf, M, 1536, 512, 512, FLAG_W16);
            attn_k<<<CH * 2, 256, 0, stream>>>(bbuf, abuf);
            gemm_f16<<<dim3(4, M / 128), 256, 0, stream>>>(
                abuf, wt_out + (size_t)i * 512 * 512, out_b + i * 512,
                h32, h32, nullptr, M, 512, 512, 512, FLAG_RES | FLAG_W32);
            ln_rows<<<M / 4, 256, 0, stream>>>(h32, ln2_w + i * 512, ln2_b + i * 512, abuf);
            gemm_f16<<<dim3(16, M / 128), 256, 0, stream>>>(
                abuf, wt_m1 + (size_t)i * 2048 * 512, mlp_b1 + i * 2048,
                nullptr, nullptr, bbuf, M, 2048, 512, 512, FLAG_W16 | FLAG_GELU);
            // at i==3 the fp32 residual stream is dead afterwards -> skip the
            // h32 write-back, emit only the f16 abuf the classifier reads
            const int fl = FLAG_RES | (i == 3 ? FLAG_W16 : FLAG_W32);
            gemm_f16<<<dim3(4, M / 128), 256, 0, stream>>>(
                bbuf, wt_m2 + (size_t)i * 512 * 2048, mlp_b2 + i * 512,
                h32, h32, abuf, M, 512, 2048, 2048, fl);
        }

        // classifier: abuf viewed as (CH, 6144) f16; split-K via fp32 partials
        gemm_f16<<<dim3(4, CH / 128, 8), 256, 0, stream>>>(
            abuf, wt_c1, nullptr, nullptr, part1, nullptr, CH, 512, 6144, 768, FLAG_PART);
        skred_k<<<(CH * 512 + 255) / 256, 256, 0, stream>>>(
            part1, cls_b1, f1, CH * 512, 512, 8);
        gemm_f16<<<dim3(1, CH / 128, 4), 256, 0, stream>>>(
            f1, wt_c2, nullptr, nullptr, part2, nullptr, CH, 128, 512, 128, FLAG_PART);
        skcls_k<<<CH / 4, 256, 0, stream>>>(
            part2, cls_b2, cls_w3, cls_b3, (float*)d_out + (size_t)c * CH * 3, CH);
    }
}